// Round 9
// baseline (1049.472 us; speedup 1.0000x reference)
//
#include <hip/hip_runtime.h>
#include <hip/hip_bf16.h>

// ModernNCA fused pipeline for MI355X (gfx950). Round 9: lean wave @ 4/SIMD.
//
// R6/R7/R8 all spilled (>170 persistent regs defeats the VGPR/AGPR split).
// R9: wave = ONE 32x32 tile at a time (5 sequential tiles), rowhalf fixed
// per wave so sume/qsv/lacc stay small. Audited persistent state ~115 regs:
// acc 16 AGPR + lacc 8 AGPR + ring 24 VGPR + sume 16 + qsv 16 + a-pf 8 +
// addr ~25. launch_bounds(512,4) pins the 128-reg cap; LDS = 64KB q + 16KB
// ed = exactly 81920 B -> 2 blocks/CU = 16 waves (4/SIMD) for latency hiding.
//
// Padding: 5000->5120 per chunk; pad rows c=0, csq=1e4 -> d>=100 -> ed==0;
// each pad adds exp(0)=1 to chunk sumexp; finalize subtracts 120.

typedef _Float16 f16x8 __attribute__((ext_vector_type(8)));
typedef _Float16 f16x4 __attribute__((ext_vector_type(4)));
typedef float f32x4 __attribute__((ext_vector_type(4)));
typedef float f32x16 __attribute__((ext_vector_type(16)));

#define MFMA16(a, b, c) __builtin_amdgcn_mfma_f32_16x16x32_f16(a, b, c, 0, 0, 0)
#define MFMA32(a, b, c) __builtin_amdgcn_mfma_f32_32x32x16_f16(a, b, c, 0, 0, 0)

// ---------------- prep: W1t/W2t transpose+cast, padded y, zero accumulators
__global__ __launch_bounds__(256) void prep_kernel(
    const float* __restrict__ W1, const float* __restrict__ W2,
    const int* __restrict__ y, _Float16* __restrict__ w1t,
    _Float16* __restrict__ w2t, int* __restrict__ ypad,
    float* __restrict__ zero_base) {
  int idx = blockIdx.x * 256 + threadIdx.x;
  if (idx < 49152) {                       // W1 [96,512] -> W1t [512,96]
    int n = idx / 96, k = idx - n * 96;
    w1t[idx] = (_Float16)W1[k * 512 + n];
  } else if (idx < 311296) {               // W2 [512,512] -> W2t [512,512]
    int j = idx - 49152;
    int n = j / 512, k = j - n * 512;
    w2t[j] = (_Float16)W2[k * 512 + n];
  } else if (idx < 413696) {               // padded candidate_y
    int j = idx - 311296;
    int ch = j / 5120, pos = j - ch * 5120;
    ypad[j] = (pos < 5000) ? y[ch * 5000 + pos] : 0;
  } else if (idx < 619520) {
    // zero: csq(102400) qsq(1024) sumexp(20480) lgts_part(81920) = 205824 f32
    zero_base[idx - 413696] = 0.0f;
  }
}

// ---------------- fused 2-layer encoder: enc = relu(x@W1+b1)@W2 + b2
template <int CHUNK_IN, int CHUNK_OUT>
__global__ __launch_bounds__(256, 2) void encode_kernel(
    const float* __restrict__ xn, const float* __restrict__ xc,
    const _Float16* __restrict__ w1t, const float* __restrict__ b1,
    const _Float16* __restrict__ w2t, const float* __restrict__ b2,
    _Float16* __restrict__ out, float* __restrict__ outsq) {
  __shared__ __align__(16) char lds_x[16384];  // 64 rows x 16 units(16B) swz
  __shared__ __align__(16) char lds_h[65536];  // 64 rows x 64 units(16B) swz

  const int t = threadIdx.x;
  const int R0 = blockIdx.x * 64;
  const int w = t >> 6, l = t & 63;
  const int l15 = l & 15, quad = l >> 4;
  const int ncol0 = w * 128;

#pragma unroll
  for (int it = 0; it < 4; it++) {
    int idx = it * 256 + t;
    int row = idx >> 4, kq = idx & 15;
    int pr = R0 + row;
    int ch = pr / CHUNK_OUT, pos = pr - ch * CHUNK_OUT;
    float v[8] = {0, 0, 0, 0, 0, 0, 0, 0};
    if (pos < CHUNK_IN && kq < 12) {
      int orig = ch * CHUNK_IN + pos;
      float4 f0, f1;
      if (kq < 8) {
        f0 = *(const float4*)&xn[orig * 64 + kq * 8];
        f1 = *(const float4*)&xn[orig * 64 + kq * 8 + 4];
      } else {
        f0 = *(const float4*)&xc[orig * 32 + (kq - 8) * 8];
        f1 = *(const float4*)&xc[orig * 32 + (kq - 8) * 8 + 4];
      }
      v[0] = f0.x; v[1] = f0.y; v[2] = f0.z; v[3] = f0.w;
      v[4] = f1.x; v[5] = f1.y; v[6] = f1.z; v[7] = f1.w;
    }
    f16x8 hv;
#pragma unroll
    for (int j = 0; j < 8; j++) hv[j] = (_Float16)v[j];
    *(f16x8*)&lds_x[row * 256 + (((kq ^ (row & 7)) & 15) << 4)] = hv;
  }
  __syncthreads();

  f32x4 acc1[8][4];
#pragma unroll
  for (int ni = 0; ni < 8; ni++)
#pragma unroll
    for (int rt = 0; rt < 4; rt++) acc1[ni][rt] = (f32x4)(0.0f);

#pragma unroll
  for (int kt = 0; kt < 3; kt++) {
    f16x8 bx[4];
#pragma unroll
    for (int rt = 0; rt < 4; rt++) {
      int row = rt * 16 + l15;
      int kq = kt * 4 + quad;
      bx[rt] = *(const f16x8*)&lds_x[row * 256 + (((kq ^ (row & 7)) & 15) << 4)];
    }
#pragma unroll
    for (int ni = 0; ni < 8; ni++) {
      f16x8 aw = *(const f16x8*)&w1t[(ncol0 + ni * 16 + l15) * 96 + kt * 32 + quad * 8];
#pragma unroll
      for (int rt = 0; rt < 4; rt++) acc1[ni][rt] = MFMA16(aw, bx[rt], acc1[ni][rt]);
    }
  }

#pragma unroll
  for (int ni = 0; ni < 8; ni++) {
    float4 b1v = *(const float4*)&b1[ncol0 + ni * 16 + quad * 4];
    int kq2 = (ncol0 >> 3) + ni * 2 + (quad >> 1);
#pragma unroll
    for (int rt = 0; rt < 4; rt++) {
      int row = rt * 16 + l15;
      f16x4 hv;
      hv[0] = (_Float16)fmaxf(acc1[ni][rt][0] + b1v.x, 0.0f);
      hv[1] = (_Float16)fmaxf(acc1[ni][rt][1] + b1v.y, 0.0f);
      hv[2] = (_Float16)fmaxf(acc1[ni][rt][2] + b1v.z, 0.0f);
      hv[3] = (_Float16)fmaxf(acc1[ni][rt][3] + b1v.w, 0.0f);
      int swz = (kq2 & ~7) | ((kq2 & 7) ^ (row & 7));
      *(f16x4*)&lds_h[row * 1024 + (swz << 4) + ((quad & 1) << 3)] = hv;
    }
  }
  __syncthreads();

  f32x4 acc2[8][4];
#pragma unroll
  for (int ni = 0; ni < 8; ni++)
#pragma unroll
    for (int rt = 0; rt < 4; rt++) acc2[ni][rt] = (f32x4)(0.0f);

  f16x8 awp[8];
#pragma unroll
  for (int ni = 0; ni < 8; ni++)
    awp[ni] = *(const f16x8*)&w2t[(ncol0 + ni * 16 + l15) * 512 + quad * 8];

  for (int kt = 0; kt < 16; kt++) {
    f16x8 awn[8];
    if (kt < 15) {
#pragma unroll
      for (int ni = 0; ni < 8; ni++)
        awn[ni] = *(const f16x8*)&w2t[(ncol0 + ni * 16 + l15) * 512 +
                                      (kt + 1) * 32 + quad * 8];
    }
    f16x8 bh[4];
#pragma unroll
    for (int rt = 0; rt < 4; rt++) {
      int row = rt * 16 + l15;
      int kq = kt * 4 + quad;
      int swz = (kq & ~7) | ((kq & 7) ^ (row & 7));
      bh[rt] = *(const f16x8*)&lds_h[row * 1024 + (swz << 4)];
    }
#pragma unroll
    for (int ni = 0; ni < 8; ni++)
#pragma unroll
      for (int rt = 0; rt < 4; rt++)
        acc2[ni][rt] = MFMA16(awp[ni], bh[rt], acc2[ni][rt]);
    if (kt < 15) {
#pragma unroll
      for (int ni = 0; ni < 8; ni++) awp[ni] = awn[ni];
    }
  }

#pragma unroll
  for (int rt = 0; rt < 4; rt++) {
    int pr = R0 + rt * 16 + l15;
    int ch = pr / CHUNK_OUT, pos = pr - ch * CHUNK_OUT;
    bool valid = pos < CHUNK_IN;
    float s = 0.0f;
#pragma unroll
    for (int ni = 0; ni < 8; ni++) {
      float4 b2v = *(const float4*)&b2[ncol0 + ni * 16 + quad * 4];
      f16x4 ov;
      if (valid) {
        ov[0] = (_Float16)(acc2[ni][rt][0] + b2v.x);
        ov[1] = (_Float16)(acc2[ni][rt][1] + b2v.y);
        ov[2] = (_Float16)(acc2[ni][rt][2] + b2v.z);
        ov[3] = (_Float16)(acc2[ni][rt][3] + b2v.w);
#pragma unroll
        for (int r = 0; r < 4; r++) {
          float cv = (float)ov[r];
          s += cv * cv;
        }
      } else {
        ov[0] = (_Float16)0.0f; ov[1] = (_Float16)0.0f;
        ov[2] = (_Float16)0.0f; ov[3] = (_Float16)0.0f;
        s += 4.0f * 19.53125f;               // 1e4 / 512 per pad element
      }
      *(f16x4*)&out[pr * 512 + ncol0 + ni * 16 + quad * 4] = ov;
    }
    s += __shfl_xor(s, 16);
    s += __shfl_xor(s, 32);
    if (quad == 0) atomicAdd(&outsq[pr], s);
  }
}

// ---------------- fused distance + reductions (lean 32x32 wave @ 4 waves/SIMD)
// 2560 blocks x 512 threads at (512,4). id: xcd=id&7 (owns cols
// [xcd*12800,+12800)), by=(id>>3)&15 (64 q-rows), m=id>>7 (0..19) ->
// g=xcd*20+m (640 cols = 20 tiles of 32). Wave w: rowhalf=w&1 (FIXED),
// coltiles (w>>1)+4i for i=0..4, processed sequentially. Per ks: 1 LDS
// a-read (prefetched 1 ahead) + 1 b-load (6-deep ring) + 1 MFMA32.
__global__ __launch_bounds__(512, 4) void dist_kernel(
    const _Float16* __restrict__ q, const _Float16* __restrict__ c,
    const float* __restrict__ qsq, const float* __restrict__ csq,
    const int* __restrict__ ypad, float* __restrict__ sumexp,
    float* __restrict__ lgts_part) {
  __shared__ __align__(16) char lds_q[65536];   // 64 rows x 64 units(16B) swz
  __shared__ __align__(16) char lds_ed[16384];  // 8 waves x 2KB (32x32 f16 swz)

  const int t = threadIdx.x, w = t >> 6, l = t & 63;
  const int l31 = l & 31, half = l >> 5;
  const int l15 = l & 15, quad = (l >> 4) & 3;
  const int id = blockIdx.x;
  const int xcd = id & 7, by = (id >> 3) & 15, m = id >> 7;   // m 0..19
  const int g = xcd * 20 + m;
  const int row0 = by * 64, chunk = g >> 3;   // 8 col-groups per 5120-chunk
  const int rowhalf = w & 1, colset = w >> 1;

  // stage q rows [row0, row0+64) into swizzled LDS (coalesced, one-time)
#pragma unroll
  for (int it = 0; it < 8; it++) {
    int idx = it * 512 + t;
    int row = idx >> 6, u = idx & 63;
    f16x8 v = *(const f16x8*)&q[(size_t)(row0 + row) * 512 + u * 8];
    int swz = (u & ~7) | ((u & 7) ^ (row & 7));
    *(f16x8*)&lds_q[row * 1024 + (swz << 4)] = v;
  }
  __syncthreads();

  // persistent per-wave state (rowhalf fixed): q norms, sumexp, logit acc
  float qsv[16], sume[16];
#pragma unroll
  for (int reg = 0; reg < 16; reg++) {
    int rr = (reg & 3) + 8 * (reg >> 2) + 4 * half;
    qsv[reg] = qsq[row0 + 32 * rowhalf + rr];
    sume[reg] = 0.0f;
  }
  f32x4 lacc[2];
  lacc[0] = (f32x4)(0.0f);
  lacc[1] = (f32x4)(0.0f);

  char* edbase = lds_ed + w * 2048;   // wave-private 32x32 f16 scratch (swz)
  const int arow = 32 * rowhalf + l31;

#pragma unroll 1
  for (int i = 0; i < 5; i++) {
    int ct = colset + 4 * i;                   // coltile 0..19
    int col0 = g * 640 + ct * 32;
    const _Float16* cb = c + (size_t)(col0 + l31) * 512 + half * 8;

    f16x8 br[6];
#pragma unroll
    for (int d = 0; d < 6; d++) br[d] = *(const f16x8*)(cb + d * 16);

    f32x16 acc = (f32x16)(0.0f);

    // a prefetch one ks ahead
    int u0 = half;
    f16x8 ap = *(const f16x8*)&lds_q[arow * 1024 +
                                     (((u0 & ~7) | ((u0 & 7) ^ (arow & 7))) << 4)];
#pragma unroll
    for (int ks = 0; ks < 32; ks++) {
      f16x8 ac = ap;
      if (ks < 31) {
        int u = (ks + 1) * 2 + half;
        int swz = (u & ~7) | ((u & 7) ^ (arow & 7));
        ap = *(const f16x8*)&lds_q[arow * 1024 + (swz << 4)];
      }
      f16x8 bc = br[ks % 6];
      if (ks < 26) br[ks % 6] = *(const f16x8*)(cb + (ks + 6) * 16);
      acc = MFMA32(ac, bc, acc);
    }

    // tile epilogue: ed = exp(-dist); sume in regs; ed -> swizzled scratch
    float cs = csq[col0 + l31];
#pragma unroll
    for (int reg = 0; reg < 16; reg++) {
      int rr = (reg & 3) + 8 * (reg >> 2) + 4 * half;   // local row 0..31
      float dd = qsv[reg] + cs - 2.0f * acc[reg];
      float ed = __expf(-sqrtf(fmaxf(dd, 0.0f)));   // pad: d>=100 -> ed==0
      sume[reg] += __expf(ed);                       // pad adds exactly 1.0
      *(_Float16*)&edbase[rr * 64 + (((l31 >> 3) ^ (rr & 3)) << 4) +
                          (l31 & 7) * 2] = (_Float16)ed;
    }

    // one-hot B-frag from ypad (classes in [0,10) -> lanes l15>=10 get zeros)
    int4 ya = *(const int4*)&ypad[col0 + quad * 8];
    int4 yb = *(const int4*)&ypad[col0 + quad * 8 + 4];
    f16x8 bf;
    bf[0] = (_Float16)(ya.x == l15 ? 1.0f : 0.0f);
    bf[1] = (_Float16)(ya.y == l15 ? 1.0f : 0.0f);
    bf[2] = (_Float16)(ya.z == l15 ? 1.0f : 0.0f);
    bf[3] = (_Float16)(ya.w == l15 ? 1.0f : 0.0f);
    bf[4] = (_Float16)(yb.x == l15 ? 1.0f : 0.0f);
    bf[5] = (_Float16)(yb.y == l15 ? 1.0f : 0.0f);
    bf[6] = (_Float16)(yb.z == l15 ? 1.0f : 0.0f);
    bf[7] = (_Float16)(yb.w == l15 ? 1.0f : 0.0f);

    // logits[row][class] += ed_tile @ onehot (same-wave DS ordering)
#pragma unroll
    for (int mt = 0; mt < 2; mt++) {
      int rowr = mt * 16 + l15;
      f16x8 af = *(const f16x8*)&edbase[rowr * 64 +
                                        ((quad ^ (rowr & 3)) << 4)];
      lacc[mt] = MFMA16(af, bf, lacc[mt]);
    }
  }

  // flush sumexp: reduce over the 32 col-lanes, 1 atomic per row
#pragma unroll
  for (int reg = 0; reg < 16; reg++) {
    float v = sume[reg];
    v += __shfl_xor(v, 1);
    v += __shfl_xor(v, 2);
    v += __shfl_xor(v, 4);
    v += __shfl_xor(v, 8);
    v += __shfl_xor(v, 16);
    if (l31 == 0) {
      int rr = (reg & 3) + 8 * (reg >> 2) + 4 * half;
      atomicAdd(&sumexp[(row0 + 32 * rowhalf + rr) * 20 + chunk], v);
    }
  }

  // flush logits to this XCD's partial array (C-layout: col=class=l15)
  if (l15 < 10) {
    float* lp = lgts_part + (size_t)xcd * 10240 + (row0 + 32 * rowhalf) * 10;
#pragma unroll
    for (int mt = 0; mt < 2; mt++)
#pragma unroll
      for (int r = 0; r < 4; r++)
        atomicAdd(&lp[(mt * 16 + quad * 4 + r) * 10 + l15], lacc[mt][r]);
  }
}

// ---------------- finalize: out[i,k] = log(Σ_xcd lgts_part) - Σ_ch log(sumexp-120)
__global__ __launch_bounds__(256) void finalize_kernel(
    const float* __restrict__ lgts_part, const float* __restrict__ sumexp,
    float* __restrict__ out) {
  int i = blockIdx.x * 256 + threadIdx.x;
  if (i >= 1024) return;
  float lse = 0.0f;
#pragma unroll
  for (int ch = 0; ch < 20; ch++) lse += logf(sumexp[i * 20 + ch] - 120.0f);
#pragma unroll
  for (int k = 0; k < 10; k++) {
    float lg = 0.0f;
#pragma unroll
    for (int x = 0; x < 8; x++) lg += lgts_part[x * 10240 + i * 10 + k];
    out[i * 10 + k] = logf(lg) - lse;
  }
}

extern "C" void kernel_launch(void* const* d_in, const int* in_sizes, int n_in,
                              void* d_out, int out_size, void* d_ws, size_t ws_size,
                              hipStream_t stream) {
  const float* x_num = (const float*)d_in[0];
  const float* x_cat = (const float*)d_in[1];
  const float* cxn   = (const float*)d_in[2];
  const float* cxc   = (const float*)d_in[3];
  const int*   cy    = (const int*)d_in[4];
  const float* W1    = (const float*)d_in[5];
  const float* b1    = (const float*)d_in[6];
  const float* W2    = (const float*)d_in[7];
  const float* b2    = (const float*)d_in[8];
  float* out = (float*)d_out;

  char* ws = (char*)d_ws;
  _Float16* c    = (_Float16*)(ws + 0);           // 102400*512*2 = 104857600
  _Float16* qe   = (_Float16*)(ws + 104857600);   // 1024*512*2   = 1048576
  _Float16* w1t  = (_Float16*)(ws + 105906176);   // 512*96*2     = 98304
  _Float16* w2t  = (_Float16*)(ws + 106004480);   // 512*512*2    = 524288
  float*    csq  = (float*)(ws + 106528768);      // 102400*4     = 409600
  float*    qsq  = (float*)(ws + 106938368);      // 1024*4       = 4096
  float*    sume = (float*)(ws + 106942464);      // 1024*20*4    = 81920
  float*    lgtp = (float*)(ws + 107024384);      // 8*1024*10*4  = 327680
  int*      ypad = (int*)(ws + 107352064);        // 102400*4     = 409600

  prep_kernel<<<2420, 256, 0, stream>>>(W1, W2, cy, w1t, w2t, ypad, csq);
  encode_kernel<5000, 5120><<<1600, 256, 0, stream>>>(cxn, cxc, w1t, b1, w2t, b2, c, csq);
  encode_kernel<(1 << 20), (1 << 20)><<<16, 256, 0, stream>>>(x_num, x_cat, w1t, b1, w2t, b2, qe, qsq);
  dist_kernel<<<2560, 512, 0, stream>>>(qe, c, qsq, csq, ypad, sume, lgtp);
  finalize_kernel<<<4, 256, 0, stream>>>(lgtp, sume, out);
}

// Round 10
// 971.388 us; speedup vs baseline: 1.0804x; 1.0804x over previous
//
#include <hip/hip_runtime.h>
#include <hip/hip_bf16.h>

// ModernNCA fused pipeline for MI355X (gfx950). Round 10: R5 + ring-6.
//
// Empirical law (R2/R5/R7/R8/R9): arch-VGPR side is capped at ~128 when
// AGPRs are live; min-waves>=4 halves it to 64. Every structure needing more
// spilled (FETCH GBs). R5 (VGPR=104, 328us) is the clean frame.
// R10 = R5 exactly, with the b-ring deepened 4->6 (+16 VGPR, ~120 total,
// under the cap; %6 is static under full unroll) and no wrap-around reloads.
// Ring coverage 112 -> 168 cyc vs ~200 cyc L2-hit latency: cuts the per-
// consume stall ~3x. Everything else is the R5-proven path.
//
// Padding: 5000->5120 per chunk; pad rows c=0, csq=1e4 -> d>=100 -> ed==0;
// each pad adds exp(0)=1 to chunk sumexp; finalize subtracts 120.

typedef _Float16 f16x8 __attribute__((ext_vector_type(8)));
typedef _Float16 f16x4 __attribute__((ext_vector_type(4)));
typedef float f32x4 __attribute__((ext_vector_type(4)));
typedef float f32x16 __attribute__((ext_vector_type(16)));

#define MFMA16(a, b, c) __builtin_amdgcn_mfma_f32_16x16x32_f16(a, b, c, 0, 0, 0)
#define MFMA32(a, b, c) __builtin_amdgcn_mfma_f32_32x32x16_f16(a, b, c, 0, 0, 0)

// ---------------- prep: W1t/W2t transpose+cast, padded y, zero accumulators
__global__ __launch_bounds__(256) void prep_kernel(
    const float* __restrict__ W1, const float* __restrict__ W2,
    const int* __restrict__ y, _Float16* __restrict__ w1t,
    _Float16* __restrict__ w2t, int* __restrict__ ypad,
    float* __restrict__ zero_base) {
  int idx = blockIdx.x * 256 + threadIdx.x;
  if (idx < 49152) {                       // W1 [96,512] -> W1t [512,96]
    int n = idx / 96, k = idx - n * 96;
    w1t[idx] = (_Float16)W1[k * 512 + n];
  } else if (idx < 311296) {               // W2 [512,512] -> W2t [512,512]
    int j = idx - 49152;
    int n = j / 512, k = j - n * 512;
    w2t[j] = (_Float16)W2[k * 512 + n];
  } else if (idx < 413696) {               // padded candidate_y
    int j = idx - 311296;
    int ch = j / 5120, pos = j - ch * 5120;
    ypad[j] = (pos < 5000) ? y[ch * 5000 + pos] : 0;
  } else if (idx < 619520) {
    // zero: csq(102400) qsq(1024) sumexp(20480) lgts_part(81920) = 205824 f32
    zero_base[idx - 413696] = 0.0f;
  }
}

// ---------------- fused 2-layer encoder: enc = relu(x@W1+b1)@W2 + b2
template <int CHUNK_IN, int CHUNK_OUT>
__global__ __launch_bounds__(256, 2) void encode_kernel(
    const float* __restrict__ xn, const float* __restrict__ xc,
    const _Float16* __restrict__ w1t, const float* __restrict__ b1,
    const _Float16* __restrict__ w2t, const float* __restrict__ b2,
    _Float16* __restrict__ out, float* __restrict__ outsq) {
  __shared__ __align__(16) char lds_x[16384];  // 64 rows x 16 units(16B) swz
  __shared__ __align__(16) char lds_h[65536];  // 64 rows x 64 units(16B) swz

  const int t = threadIdx.x;
  const int R0 = blockIdx.x * 64;
  const int w = t >> 6, l = t & 63;
  const int l15 = l & 15, quad = l >> 4;
  const int ncol0 = w * 128;

#pragma unroll
  for (int it = 0; it < 4; it++) {
    int idx = it * 256 + t;
    int row = idx >> 4, kq = idx & 15;
    int pr = R0 + row;
    int ch = pr / CHUNK_OUT, pos = pr - ch * CHUNK_OUT;
    float v[8] = {0, 0, 0, 0, 0, 0, 0, 0};
    if (pos < CHUNK_IN && kq < 12) {
      int orig = ch * CHUNK_IN + pos;
      float4 f0, f1;
      if (kq < 8) {
        f0 = *(const float4*)&xn[orig * 64 + kq * 8];
        f1 = *(const float4*)&xn[orig * 64 + kq * 8 + 4];
      } else {
        f0 = *(const float4*)&xc[orig * 32 + (kq - 8) * 8];
        f1 = *(const float4*)&xc[orig * 32 + (kq - 8) * 8 + 4];
      }
      v[0] = f0.x; v[1] = f0.y; v[2] = f0.z; v[3] = f0.w;
      v[4] = f1.x; v[5] = f1.y; v[6] = f1.z; v[7] = f1.w;
    }
    f16x8 hv;
#pragma unroll
    for (int j = 0; j < 8; j++) hv[j] = (_Float16)v[j];
    *(f16x8*)&lds_x[row * 256 + (((kq ^ (row & 7)) & 15) << 4)] = hv;
  }
  __syncthreads();

  f32x4 acc1[8][4];
#pragma unroll
  for (int ni = 0; ni < 8; ni++)
#pragma unroll
    for (int rt = 0; rt < 4; rt++) acc1[ni][rt] = (f32x4)(0.0f);

#pragma unroll
  for (int kt = 0; kt < 3; kt++) {
    f16x8 bx[4];
#pragma unroll
    for (int rt = 0; rt < 4; rt++) {
      int row = rt * 16 + l15;
      int kq = kt * 4 + quad;
      bx[rt] = *(const f16x8*)&lds_x[row * 256 + (((kq ^ (row & 7)) & 15) << 4)];
    }
#pragma unroll
    for (int ni = 0; ni < 8; ni++) {
      f16x8 aw = *(const f16x8*)&w1t[(ncol0 + ni * 16 + l15) * 96 + kt * 32 + quad * 8];
#pragma unroll
      for (int rt = 0; rt < 4; rt++) acc1[ni][rt] = MFMA16(aw, bx[rt], acc1[ni][rt]);
    }
  }

#pragma unroll
  for (int ni = 0; ni < 8; ni++) {
    float4 b1v = *(const float4*)&b1[ncol0 + ni * 16 + quad * 4];
    int kq2 = (ncol0 >> 3) + ni * 2 + (quad >> 1);
#pragma unroll
    for (int rt = 0; rt < 4; rt++) {
      int row = rt * 16 + l15;
      f16x4 hv;
      hv[0] = (_Float16)fmaxf(acc1[ni][rt][0] + b1v.x, 0.0f);
      hv[1] = (_Float16)fmaxf(acc1[ni][rt][1] + b1v.y, 0.0f);
      hv[2] = (_Float16)fmaxf(acc1[ni][rt][2] + b1v.z, 0.0f);
      hv[3] = (_Float16)fmaxf(acc1[ni][rt][3] + b1v.w, 0.0f);
      int swz = (kq2 & ~7) | ((kq2 & 7) ^ (row & 7));
      *(f16x4*)&lds_h[row * 1024 + (swz << 4) + ((quad & 1) << 3)] = hv;
    }
  }
  __syncthreads();

  f32x4 acc2[8][4];
#pragma unroll
  for (int ni = 0; ni < 8; ni++)
#pragma unroll
    for (int rt = 0; rt < 4; rt++) acc2[ni][rt] = (f32x4)(0.0f);

  f16x8 awp[8];
#pragma unroll
  for (int ni = 0; ni < 8; ni++)
    awp[ni] = *(const f16x8*)&w2t[(ncol0 + ni * 16 + l15) * 512 + quad * 8];

  for (int kt = 0; kt < 16; kt++) {
    f16x8 awn[8];
    if (kt < 15) {
#pragma unroll
      for (int ni = 0; ni < 8; ni++)
        awn[ni] = *(const f16x8*)&w2t[(ncol0 + ni * 16 + l15) * 512 +
                                      (kt + 1) * 32 + quad * 8];
    }
    f16x8 bh[4];
#pragma unroll
    for (int rt = 0; rt < 4; rt++) {
      int row = rt * 16 + l15;
      int kq = kt * 4 + quad;
      int swz = (kq & ~7) | ((kq & 7) ^ (row & 7));
      bh[rt] = *(const f16x8*)&lds_h[row * 1024 + (swz << 4)];
    }
#pragma unroll
    for (int ni = 0; ni < 8; ni++)
#pragma unroll
      for (int rt = 0; rt < 4; rt++)
        acc2[ni][rt] = MFMA16(awp[ni], bh[rt], acc2[ni][rt]);
    if (kt < 15) {
#pragma unroll
      for (int ni = 0; ni < 8; ni++) awp[ni] = awn[ni];
    }
  }

#pragma unroll
  for (int rt = 0; rt < 4; rt++) {
    int pr = R0 + rt * 16 + l15;
    int ch = pr / CHUNK_OUT, pos = pr - ch * CHUNK_OUT;
    bool valid = pos < CHUNK_IN;
    float s = 0.0f;
#pragma unroll
    for (int ni = 0; ni < 8; ni++) {
      float4 b2v = *(const float4*)&b2[ncol0 + ni * 16 + quad * 4];
      f16x4 ov;
      if (valid) {
        ov[0] = (_Float16)(acc2[ni][rt][0] + b2v.x);
        ov[1] = (_Float16)(acc2[ni][rt][1] + b2v.y);
        ov[2] = (_Float16)(acc2[ni][rt][2] + b2v.z);
        ov[3] = (_Float16)(acc2[ni][rt][3] + b2v.w);
#pragma unroll
        for (int r = 0; r < 4; r++) {
          float cv = (float)ov[r];
          s += cv * cv;
        }
      } else {
        ov[0] = (_Float16)0.0f; ov[1] = (_Float16)0.0f;
        ov[2] = (_Float16)0.0f; ov[3] = (_Float16)0.0f;
        s += 4.0f * 19.53125f;               // 1e4 / 512 per pad element
      }
      *(f16x4*)&out[pr * 512 + ncol0 + ni * 16 + quad * 4] = ov;
    }
    s += __shfl_xor(s, 16);
    s += __shfl_xor(s, 32);
    if (quad == 0) atomicAdd(&outsq[pr], s);
  }
}

// ---------------- fused distance + reductions (R5 frame, ring depth 6)
// 1280 blocks x 512 threads at (512,2). id: xcd=id&7 (owns cols
// [xcd*12800,+12800)), by=(id>>3)&15 (64 q-rows), m=id>>7 -> g=xcd*10+m
// (1280 cols; wave w does tiles w, w+8, ... 5 tiles of 32 cols x 64 rows).
__global__ __launch_bounds__(512, 2) void dist_kernel(
    const _Float16* __restrict__ q, const _Float16* __restrict__ c,
    const float* __restrict__ qsq, const float* __restrict__ csq,
    const int* __restrict__ ypad, float* __restrict__ sumexp,
    float* __restrict__ lgts_part) {
  __shared__ __align__(16) char lds_q[65536];   // 64 rows x 64 units(16B) swz
  __shared__ __align__(16) char lds_ed[32768];  // 8 waves x 4KB (64x32 f16 swz)
  __shared__ float lds_logit[640];              // 64 rows x 10 classes
  __shared__ float lds_qsq[64];

  const int t = threadIdx.x, w = t >> 6, l = t & 63;
  const int l31 = l & 31, half = l >> 5;
  const int l15 = l & 15, quad = (l >> 4) & 3;
  const int id = blockIdx.x;
  const int xcd = id & 7, by = (id >> 3) & 15, m = id >> 7;
  const int g = xcd * 10 + m;
  const int row0 = by * 64, chunk = g >> 2;   // 4 col-groups per 5120-chunk

  for (int i = t; i < 640; i += 512) lds_logit[i] = 0.0f;
  if (t < 64) lds_qsq[t] = qsq[row0 + t];

  // stage q rows [row0, row0+64) into swizzled LDS (coalesced, one-time)
#pragma unroll
  for (int it = 0; it < 8; it++) {
    int idx = it * 512 + t;
    int row = idx >> 6, u = idx & 63;
    f16x8 v = *(const f16x8*)&q[(size_t)(row0 + row) * 512 + u * 8];
    int swz = (u & ~7) | ((u & 7) ^ (row & 7));
    *(f16x8*)&lds_q[row * 1024 + (swz << 4)] = v;
  }
  __syncthreads();

  float sume0[16], sume1[16];
  f32x4 lacc[4];
#pragma unroll
  for (int reg = 0; reg < 16; reg++) { sume0[reg] = 0.0f; sume1[reg] = 0.0f; }
#pragma unroll
  for (int mt = 0; mt < 4; mt++) lacc[mt] = (f32x4)(0.0f);

  char* edbase = lds_ed + w * 4096;   // wave-private 64x32 f16 scratch (swz)

  for (int tile = w; tile < 40; tile += 8) {
    int col0 = g * 1280 + tile * 32;
    const _Float16* cb = c + (size_t)(col0 + l31) * 512 + half * 8;

    f32x16 acc0 = (f32x16)(0.0f), acc1 = (f32x16)(0.0f);
    f16x8 br[6];
#pragma unroll
    for (int i = 0; i < 6; i++) br[i] = *(const f16x8*)(cb + i * 16);

#pragma unroll
    for (int ks = 0; ks < 32; ks++) {
      f16x8 bc = br[ks % 6];
      if (ks < 26) br[ks % 6] = *(const f16x8*)(cb + (ks + 6) * 16);
      int u = ks * 2 + half;
      int swz = (u & ~7) | ((u & 7) ^ (l31 & 7));   // (32+l31)&7 == l31&7
      f16x8 a0 = *(const f16x8*)&lds_q[l31 * 1024 + (swz << 4)];
      f16x8 a1 = *(const f16x8*)&lds_q[(32 + l31) * 1024 + (swz << 4)];
      acc0 = MFMA32(a0, bc, acc0);
      acc1 = MFMA32(a1, bc, acc1);
    }

    // epilogue: ed = exp(-dist); sume in regs; ed tile -> swizzled scratch
    float cs = csq[col0 + l31];
#pragma unroll
    for (int reg = 0; reg < 16; reg++) {
      int rr = (reg & 3) + 8 * (reg >> 2) + 4 * half;
      float ed0 = __expf(-sqrtf(fmaxf(lds_qsq[rr] + cs - 2.0f * acc0[reg], 0.0f)));
      float ed1 = __expf(-sqrtf(fmaxf(lds_qsq[32 + rr] + cs - 2.0f * acc1[reg], 0.0f)));
      sume0[reg] += __expf(ed0);     // pad cols: ed==0 -> adds exactly 1.0
      sume1[reg] += __expf(ed1);
      *(_Float16*)&edbase[rr * 64 + (((l31 >> 3) ^ (rr & 3)) << 4) +
                          (l31 & 7) * 2] = (_Float16)ed0;
      *(_Float16*)&edbase[(32 + rr) * 64 + (((l31 >> 3) ^ (rr & 3)) << 4) +
                          (l31 & 7) * 2] = (_Float16)ed1;
    }

    // one-hot B-frag from ypad (classes in [0,10) -> lanes l15>=10 get zeros)
    int4 ya = *(const int4*)&ypad[col0 + quad * 8];
    int4 yb = *(const int4*)&ypad[col0 + quad * 8 + 4];
    f16x8 bf;
    bf[0] = (_Float16)(ya.x == l15 ? 1.0f : 0.0f);
    bf[1] = (_Float16)(ya.y == l15 ? 1.0f : 0.0f);
    bf[2] = (_Float16)(ya.z == l15 ? 1.0f : 0.0f);
    bf[3] = (_Float16)(ya.w == l15 ? 1.0f : 0.0f);
    bf[4] = (_Float16)(yb.x == l15 ? 1.0f : 0.0f);
    bf[5] = (_Float16)(yb.y == l15 ? 1.0f : 0.0f);
    bf[6] = (_Float16)(yb.z == l15 ? 1.0f : 0.0f);
    bf[7] = (_Float16)(yb.w == l15 ? 1.0f : 0.0f);

    // logits[row][class] += ed_tile @ onehot (same-wave DS ordering)
#pragma unroll
    for (int mt = 0; mt < 4; mt++) {
      int rowr = mt * 16 + l15;
      f16x8 af = *(const f16x8*)&edbase[rowr * 64 +
                                        ((quad ^ (rowr & 3)) << 4)];
      lacc[mt] = MFMA16(af, bf, lacc[mt]);
    }
  }

  // flush sumexp: reduce over the 32 col-lanes, 1 atomic per row
#pragma unroll
  for (int reg = 0; reg < 16; reg++) {
    float v0 = sume0[reg], v1 = sume1[reg];
    v0 += __shfl_xor(v0, 1);  v1 += __shfl_xor(v1, 1);
    v0 += __shfl_xor(v0, 2);  v1 += __shfl_xor(v1, 2);
    v0 += __shfl_xor(v0, 4);  v1 += __shfl_xor(v1, 4);
    v0 += __shfl_xor(v0, 8);  v1 += __shfl_xor(v1, 8);
    v0 += __shfl_xor(v0, 16); v1 += __shfl_xor(v1, 16);
    if (l31 == 0) {
      int rr = (reg & 3) + 8 * (reg >> 2) + 4 * half;
      atomicAdd(&sumexp[(row0 + rr) * 20 + chunk], v0);
      atomicAdd(&sumexp[(row0 + 32 + rr) * 20 + chunk], v1);
    }
  }

  // flush logits: lacc (C-layout: col=class=l15, row=mt*16+quad*4+r)
  if (l15 < 10) {
#pragma unroll
    for (int mt = 0; mt < 4; mt++)
#pragma unroll
      for (int r = 0; r < 4; r++)
        atomicAdd(&lds_logit[(mt * 16 + quad * 4 + r) * 10 + l15], lacc[mt][r]);
  }
  __syncthreads();
  float* lp = lgts_part + (size_t)xcd * 10240 + row0 * 10;
  for (int i = t; i < 640; i += 512) atomicAdd(&lp[i], lds_logit[i]);
}

// ---------------- finalize: out[i,k] = log(Σ_xcd lgts_part) - Σ_ch log(sumexp-120)
__global__ __launch_bounds__(256) void finalize_kernel(
    const float* __restrict__ lgts_part, const float* __restrict__ sumexp,
    float* __restrict__ out) {
  int i = blockIdx.x * 256 + threadIdx.x;
  if (i >= 1024) return;
  float lse = 0.0f;
#pragma unroll
  for (int ch = 0; ch < 20; ch++) lse += logf(sumexp[i * 20 + ch] - 120.0f);
#pragma unroll
  for (int k = 0; k < 10; k++) {
    float lg = 0.0f;
#pragma unroll
    for (int x = 0; x < 8; x++) lg += lgts_part[x * 10240 + i * 10 + k];
    out[i * 10 + k] = logf(lg) - lse;
  }
}

extern "C" void kernel_launch(void* const* d_in, const int* in_sizes, int n_in,
                              void* d_out, int out_size, void* d_ws, size_t ws_size,
                              hipStream_t stream) {
  const float* x_num = (const float*)d_in[0];
  const float* x_cat = (const float*)d_in[1];
  const float* cxn   = (const float*)d_in[2];
  const float* cxc   = (const float*)d_in[3];
  const int*   cy    = (const int*)d_in[4];
  const float* W1    = (const float*)d_in[5];
  const float* b1    = (const float*)d_in[6];
  const float* W2    = (const float*)d_in[7];
  const float* b2    = (const float*)d_in[8];
  float* out = (float*)d_out;

  char* ws = (char*)d_ws;
  _Float16* c    = (_Float16*)(ws + 0);           // 102400*512*2 = 104857600
  _Float16* qe   = (_Float16*)(ws + 104857600);   // 1024*512*2   = 1048576
  _Float16* w1t  = (_Float16*)(ws + 105906176);   // 512*96*2     = 98304
  _Float16* w2t  = (_Float16*)(ws + 106004480);   // 512*512*2    = 524288
  float*    csq  = (float*)(ws + 106528768);      // 102400*4     = 409600
  float*    qsq  = (float*)(ws + 106938368);      // 1024*4       = 4096
  float*    sume = (float*)(ws + 106942464);      // 1024*20*4    = 81920
  float*    lgtp = (float*)(ws + 107024384);      // 8*1024*10*4  = 327680
  int*      ypad = (int*)(ws + 107352064);        // 102400*4     = 409600

  prep_kernel<<<2420, 256, 0, stream>>>(W1, W2, cy, w1t, w2t, ypad, csq);
  encode_kernel<5000, 5120><<<1600, 256, 0, stream>>>(cxn, cxc, w1t, b1, w2t, b2, c, csq);
  encode_kernel<(1 << 20), (1 << 20)><<<16, 256, 0, stream>>>(x_num, x_cat, w1t, b1, w2t, b2, qe, qsq);
  dist_kernel<<<1280, 512, 0, stream>>>(qe, c, qsq, csq, ypad, sume, lgtp);
  finalize_kernel<<<4, 256, 0, stream>>>(lgtp, sume, out);
}